// Round 1
// baseline (868.231 us; speedup 1.0000x reference)
//
#include <hip/hip_runtime.h>

// stackCLSTM: T=32, B=128, I=64, H=128, E=4, N_TRAP=100
// ws layout (float offsets):
//   W_all  [64][3072]            @ 0         (196608)  x-part weights (xh cols 0..511, gates 512..3071)
//   bias   [3072]                @ 196608    (3072)
//   Whh_p  [128][512][4]         @ 199680    (262144)  h-part of Wh, packed 4 k-rows per float4
//   Wgp    [(e*32+j4)*5+g][128][4] @ 461824  (327680)  h-part of gate weights, packed
//   XG     [4096][3072]          @ 789504    (12582912) per-(t,b) x-projections
//   Gst    [4][4096*512]         @ 13372416  (8388608)  g, diff, delta, o  for trapezoid
#define OFF_WALL   0
#define OFF_BIAS   196608
#define OFF_WHHP   199680
#define OFF_WGP    461824
#define OFF_XG     789504
#define OFF_GST    13372416
#define GST_PLANE  2097152

__device__ __forceinline__ float fast_sig(float x) {
    return __fdividef(1.f, 1.f + __expf(-x));
}

// ---------------- K0: pack weights ----------------
__global__ __launch_bounds__(256) void k0_pack(
    const float* __restrict__ Wh_w, const float* __restrict__ Wh_b,
    const float* __restrict__ Wi_w, const float* __restrict__ Wi_b,
    const float* __restrict__ Wf_w, const float* __restrict__ Wf_b,
    const float* __restrict__ Wd_w, const float* __restrict__ Wd_b,
    const float* __restrict__ Wg_w, const float* __restrict__ Wg_b,
    const float* __restrict__ Wo_w, const float* __restrict__ Wo_b,
    float* __restrict__ ws)
{
    const float* gw[5] = {Wi_w, Wf_w, Wd_w, Wg_w, Wo_w};
    const float* gb[5] = {Wi_b, Wf_b, Wd_b, Wg_b, Wo_b};
    int idx = blockIdx.x * 256 + threadIdx.x;
    if (idx < 196608) {            // W_all [r<64][col<3072]
        int r = idx / 3072, col = idx - r * 3072;
        float v;
        if (col < 512) {
            // cat = [x,h0,x,h1,x,h2,x,h3]: x occupies rows m*192+r, r<64
            v = Wh_w[r * 512 + col] + Wh_w[(192 + r) * 512 + col]
              + Wh_w[(384 + r) * 512 + col] + Wh_w[(576 + r) * 512 + col];
        } else {
            int q = col - 512;
            int e = q / 640;
            int rem = q - e * 640;
            int g = rem >> 7, h = rem & 127;
            v = gw[g][(e * 192 + r) * 128 + h];
        }
        ws[OFF_WALL + idx] = v;
    } else if (idx < 196608 + 262144) {  // Whh_p
        int i = idx - 196608;
        int d4 = i >> 11;
        int n = (i >> 2) & 511;
        int q = i & 3;
        int d = d4 * 4 + q;                      // d = m*128 + j
        int row = (d >> 7) * 192 + 64 + (d & 127);
        ws[OFF_WHHP + i] = Wh_w[row * 512 + n];
    } else if (idx < 196608 + 262144 + 327680) { // Wgp
        int i = idx - (196608 + 262144);
        int q = i & 3;
        int h = (i >> 2) & 127;
        int rest = i >> 9;        // (e*32+j4)*5+g
        int g = rest % 5;
        int ej = rest / 5;
        int e = ej >> 5, j4 = ej & 31;
        int j = j4 * 4 + q;
        ws[OFF_WGP + i] = gw[g][(e * 192 + 64 + j) * 128 + h];
    }
    if (idx < 3072) {              // bias
        float v;
        if (idx < 512) v = Wh_b[idx];
        else {
            int q = idx - 512;
            int e = q / 640;
            int rem = q - e * 640;
            int g = rem >> 7, h = rem & 127;
            v = gb[g][e * 128 + h];
        }
        ws[OFF_BIAS + idx] = v;
    }
}

// ---------------- K1: x projections  XG[4096][3072] = X[4096][64] @ W_all + bias ----------------
__global__ __launch_bounds__(256) void k1_xproj(
    const float* __restrict__ x, const float* wsr, float* XG)
{
    __shared__ __align__(16) float XT[64 * 68];   // [k][i], padded
    const float* W_all = wsr + OFF_WALL;
    const float* bias  = wsr + OFF_BIAS;
    int bid = blockIdx.x;
    int ct = bid % 48, rt = bid / 48;
    int r0 = rt * 64, c0 = ct * 64;
    for (int p = threadIdx.x; p < 4096; p += 256) {
        int i = p >> 6, k = p & 63;
        XT[k * 68 + i] = x[(r0 + i) * 64 + k];
    }
    __syncthreads();
    int col = c0 + (threadIdx.x & 63);
    int iq = threadIdx.x >> 6;   // 0..3 -> rows iq*16..+15
    float acc[16];
    #pragma unroll
    for (int r = 0; r < 16; r++) acc[r] = 0.f;
    const float* wp = W_all + col;
    #pragma unroll 4
    for (int k = 0; k < 64; k++) {
        float w = wp[k * 3072];
        const float4* xt4 = reinterpret_cast<const float4*>(&XT[k * 68 + iq * 16]);
        #pragma unroll
        for (int r4 = 0; r4 < 4; r4++) {
            float4 xv = xt4[r4];
            acc[r4 * 4 + 0] = fmaf(xv.x, w, acc[r4 * 4 + 0]);
            acc[r4 * 4 + 1] = fmaf(xv.y, w, acc[r4 * 4 + 1]);
            acc[r4 * 4 + 2] = fmaf(xv.z, w, acc[r4 * 4 + 2]);
            acc[r4 * 4 + 3] = fmaf(xv.w, w, acc[r4 * 4 + 3]);
        }
    }
    float bv = bias[col];
    #pragma unroll
    for (int r = 0; r < 16; r++) {
        int row = r0 + iq * 16 + r;
        XG[row * 3072 + col] = acc[r] + bv;
    }
}

// ---------------- K2: sequential recurrence, 1 block = 2 batch elems ----------------
__global__ __launch_bounds__(512) void k2_recur(
    const float4* __restrict__ Whh_p,   // [128 j4][512 n] float4
    const float4* __restrict__ Wgp,     // [(e*32+j4)*5+g][128 h] float4
    const float* __restrict__ XG,
    const float* __restrict__ dt_time,
    const float* __restrict__ alpha,
    float* __restrict__ Gst,
    float* __restrict__ lam_out)
{
    __shared__ __align__(16) float hc[2][512];
    __shared__ __align__(16) float hs[2][512];
    __shared__ float red[16];
    const int tid = threadIdx.x;
    const int b0 = blockIdx.x * 2;
    const int e = tid >> 7;
    const float av = alpha[tid];
    float c0 = 0.f, c1 = 0.f;
    hc[0][tid] = 0.f;
    hc[1][tid] = 0.f;
    const float4* wph = Whh_p + tid;
    const float4* wpg = Wgp + (e * 160) * 128 + (tid & 127);
    __syncthreads();
    for (int t = 0; t < 32; t++) {
        const int row0 = t * 128 + b0;
        float a0 = XG[row0 * 3072 + tid];
        float a1 = XG[(row0 + 1) * 3072 + tid];
        const float4* h40 = reinterpret_cast<const float4*>(hc[0]);
        const float4* h41 = reinterpret_cast<const float4*>(hc[1]);
        #pragma unroll 8
        for (int j4 = 0; j4 < 128; j4++) {
            float4 w = wph[j4 * 512];
            float4 v0 = h40[j4];
            float4 v1 = h41[j4];
            a0 = fmaf(v0.x, w.x, a0); a0 = fmaf(v0.y, w.y, a0);
            a0 = fmaf(v0.z, w.z, a0); a0 = fmaf(v0.w, w.w, a0);
            a1 = fmaf(v1.x, w.x, a1); a1 = fmaf(v1.y, w.y, a1);
            a1 = fmaf(v1.z, w.z, a1); a1 = fmaf(v1.w, w.w, a1);
        }
        hs[0][tid] = a0;
        hs[1][tid] = a1;
        __syncthreads();
        float acc0[5], acc1[5];
        {
            const float* xp0 = XG + row0 * 3072 + 512 + e * 640 + (tid & 127);
            const float* xp1 = xp0 + 3072;
            #pragma unroll
            for (int g = 0; g < 5; g++) { acc0[g] = xp0[g * 128]; acc1[g] = xp1[g * 128]; }
        }
        const float4* s40 = reinterpret_cast<const float4*>(&hs[0][e * 128]);
        const float4* s41 = reinterpret_cast<const float4*>(&hs[1][e * 128]);
        #pragma unroll 4
        for (int j4 = 0; j4 < 32; j4++) {
            float4 v0 = s40[j4];
            float4 v1 = s41[j4];
            #pragma unroll
            for (int g = 0; g < 5; g++) {
                float4 w = wpg[(j4 * 5 + g) * 128];
                acc0[g] = fmaf(v0.x, w.x, acc0[g]); acc0[g] = fmaf(v0.y, w.y, acc0[g]);
                acc0[g] = fmaf(v0.z, w.z, acc0[g]); acc0[g] = fmaf(v0.w, w.w, acc0[g]);
                acc1[g] = fmaf(v1.x, w.x, acc1[g]); acc1[g] = fmaf(v1.y, w.y, acc1[g]);
                acc1[g] = fmaf(v1.z, w.z, acc1[g]); acc1[g] = fmaf(v1.w, w.w, acc1[g]);
            }
        }
        const float dtv0 = dt_time[t * 128 + b0];
        const float dtv1 = dt_time[t * 128 + b0 + 1];
        // slot 0
        float ig = fast_sig(acc0[0]);
        float fg = fast_sig(acc0[1]);
        float dl = __expf(acc0[2]);
        float gt = tanhf(acc0[3]);
        float og = fast_sig(acc0[4]);
        float gc = fmaf(fg, c0, ig * gt);
        float df = c0 - gc;
        c0 = fmaf(df, __expf(-dl * dtv0), gc);
        float hn0 = og * tanhf(c0);
        int go = row0 * 512 + tid;
        Gst[0 * GST_PLANE + go] = gc;
        Gst[1 * GST_PLANE + go] = df;
        Gst[2 * GST_PLANE + go] = dl;
        Gst[3 * GST_PLANE + go] = og;
        // slot 1
        float ig1 = fast_sig(acc1[0]);
        float fg1 = fast_sig(acc1[1]);
        float dl1 = __expf(acc1[2]);
        float gt1 = tanhf(acc1[3]);
        float og1 = fast_sig(acc1[4]);
        float gc1 = fmaf(fg1, c1, ig1 * gt1);
        float df1 = c1 - gc1;
        c1 = fmaf(df1, __expf(-dl1 * dtv1), gc1);
        float hn1 = og1 * tanhf(c1);
        int go1 = go + 512;
        Gst[0 * GST_PLANE + go1] = gc1;
        Gst[1 * GST_PLANE + go1] = df1;
        Gst[2 * GST_PLANE + go1] = dl1;
        Gst[3 * GST_PLANE + go1] = og1;
        hc[0][tid] = hn0;
        hc[1][tid] = hn1;
        // lambda = sum_h alpha*h_new  (per e, per slot)
        float l0 = av * hn0;
        float l1 = av * hn1;
        #pragma unroll
        for (int off = 32; off > 0; off >>= 1) {
            l0 += __shfl_down(l0, off, 64);
            l1 += __shfl_down(l1, off, 64);
        }
        const int wv = tid >> 6;
        if ((tid & 63) == 0) { red[wv * 2] = l0; red[wv * 2 + 1] = l1; }
        __syncthreads();
        if (tid < 8) {
            int ee = tid >> 1, bs = tid & 1;
            float lam = red[ee * 4 + bs] + red[ee * 4 + 2 + bs];
            lam_out[(row0 + bs) * 4 + ee] = lam;
        }
    }
}

// ---------------- K3: trapezoid integrals, 1 block per (t,b) ----------------
__global__ __launch_bounds__(256) void k3_trap(
    const float* __restrict__ Gst, const float* __restrict__ dt_time,
    const float* __restrict__ alpha, float* __restrict__ integ_out)
{
    __shared__ float red[4][2];
    const int row = blockIdx.x;          // t*128+b
    const int tid = threadIdx.x;
    const float dtv = dt_time[row];
    const int base = row * 512;
    const int pA = tid, pB = tid + 256;
    float gcA = Gst[0 * GST_PLANE + base + pA];
    float gcB = Gst[0 * GST_PLANE + base + pB];
    float dfA = Gst[1 * GST_PLANE + base + pA];
    float dfB = Gst[1 * GST_PLANE + base + pB];
    float dlA = Gst[2 * GST_PLANE + base + pA];
    float dlB = Gst[2 * GST_PLANE + base + pB];
    float oA  = Gst[3 * GST_PLANE + base + pA];
    float oB  = Gst[3 * GST_PLANE + base + pB];
    float aoA = alpha[pA] * oA;
    float aoB = alpha[pB] * oB;
    // tanh(x) = 1 - 2/(exp(2x)+1); cv = g + diff*E, E_k = exp(-delta*dt*k/100) geometric
    float g2A = 2.f * gcA, d2A = 2.f * dfA;
    float g2B = 2.f * gcB, d2B = 2.f * dfB;
    float qA = dlA * dtv, qB = dlB * dtv;
    float rA = __expf(-qA * 0.01f);
    float rB = __expf(-qB * 0.01f);
    float E100A = __expf(-qA);
    float E100B = __expf(-qB);
    float sA = 0.5f * (__fdividef(1.f, __expf(g2A + d2A) + 1.f)
                     + __fdividef(1.f, __expf(fmaf(d2A, E100A, g2A)) + 1.f));
    float sB = 0.5f * (__fdividef(1.f, __expf(g2B + d2B) + 1.f)
                     + __fdividef(1.f, __expf(fmaf(d2B, E100B, g2B)) + 1.f));
    float EA = rA, EB = rB;
    for (int k = 1; k < 100; k++) {
        sA += __fdividef(1.f, __expf(fmaf(d2A, EA, g2A)) + 1.f);
        sB += __fdividef(1.f, __expf(fmaf(d2B, EB, g2B)) + 1.f);
        EA *= rA;
        EB *= rB;
    }
    // sum_k w_k tanh_k = 100 - 2*s
    float vA = aoA * (100.f - 2.f * sA);
    float vB = aoB * (100.f - 2.f * sB);
    #pragma unroll
    for (int off = 32; off > 0; off >>= 1) {
        vA += __shfl_down(vA, off, 64);
        vB += __shfl_down(vB, off, 64);
    }
    const int wv = tid >> 6;
    if ((tid & 63) == 0) { red[wv][0] = vA; red[wv][1] = vB; }
    __syncthreads();
    if (tid < 4) {
        float v = (tid < 2) ? (red[2 * tid][0] + red[2 * tid + 1][0])
                            : (red[2 * (tid - 2)][1] + red[2 * (tid - 2) + 1][1]);
        integ_out[row * 4 + tid] = v * (dtv * 0.01f);
    }
}

extern "C" void kernel_launch(void* const* d_in, const int* in_sizes, int n_in,
                              void* d_out, int out_size, void* d_ws, size_t ws_size,
                              hipStream_t stream)
{
    const float* x_time  = (const float*)d_in[0];
    const float* dt_time = (const float*)d_in[1];
    const float* Wh_w = (const float*)d_in[2];
    const float* Wh_b = (const float*)d_in[3];
    const float* Wi_w = (const float*)d_in[4];
    const float* Wi_b = (const float*)d_in[5];
    const float* Wf_w = (const float*)d_in[6];
    const float* Wf_b = (const float*)d_in[7];
    const float* Wd_w = (const float*)d_in[8];
    const float* Wd_b = (const float*)d_in[9];
    const float* Wg_w = (const float*)d_in[10];
    const float* Wg_b = (const float*)d_in[11];
    const float* Wo_w = (const float*)d_in[12];
    const float* Wo_b = (const float*)d_in[13];
    const float* alpha = (const float*)d_in[14];

    float* ws = (float*)d_ws;
    float* XG   = ws + OFF_XG;
    float* Gst  = ws + OFF_GST;
    float* lam_out   = (float*)d_out;
    float* integ_out = lam_out + 32 * 128 * 4;

    k0_pack<<<3072, 256, 0, stream>>>(Wh_w, Wh_b, Wi_w, Wi_b, Wf_w, Wf_b,
                                      Wd_w, Wd_b, Wg_w, Wg_b, Wo_w, Wo_b, ws);
    k1_xproj<<<3072, 256, 0, stream>>>(x_time, ws, XG);
    k2_recur<<<64, 512, 0, stream>>>(
        (const float4*)(ws + OFF_WHHP), (const float4*)(ws + OFF_WGP),
        XG, dt_time, alpha, Gst, lam_out);
    k3_trap<<<4096, 256, 0, stream>>>(Gst, dt_time, alpha, integ_out);
}

// Round 2
// 777.521 us; speedup vs baseline: 1.1167x; 1.1167x over previous
//
#include <hip/hip_runtime.h>

// stackCLSTM: T=32, B=128, I=64, H=128, E=4, N_TRAP=100
// ws layout (float offsets):
//   W_all  [64][3072]              @ 0         (196608)  x-part weights
//   bias   [3072]                  @ 196608    (3072)
//   WhhE   [e][j4 128][col 128][4] @ 199680    (262144)  h-part of Wh, e-major, float4 over j-quad
//   WgE    [(e*32+j4)*5+g][128][4] @ 461824    (327680)  h-part of gate weights
//   XG     [4096][3072]            @ 789504    (12582912) per-(t,b) x-projections (+bias)
//   Gst    [4][4096*512]           @ 13372416  (8388608)  g, diff, delta, o for trapezoid
//   hbuf   [2][64][2][512]         @ 21761024  (131072)   double-buffered h state
//   flags  [64][32] int            @ 21892096  (2048)     per-group per-step sync counters
#define OFF_WALL   0
#define OFF_BIAS   196608
#define OFF_WHHP   199680
#define OFF_WGP    461824
#define OFF_XG     789504
#define OFF_GST    13372416
#define OFF_HBUF   21761024
#define OFF_FLAGS  21892096
#define GST_PLANE  2097152

__device__ __forceinline__ float fast_sig(float x) {
    return __fdividef(1.f, 1.f + __expf(-x));
}

// ---------------- K0: pack weights + zero flags ----------------
__global__ __launch_bounds__(256) void k0_pack(
    const float* __restrict__ Wh_w, const float* __restrict__ Wh_b,
    const float* __restrict__ Wi_w, const float* __restrict__ Wi_b,
    const float* __restrict__ Wf_w, const float* __restrict__ Wf_b,
    const float* __restrict__ Wd_w, const float* __restrict__ Wd_b,
    const float* __restrict__ Wg_w, const float* __restrict__ Wg_b,
    const float* __restrict__ Wo_w, const float* __restrict__ Wo_b,
    float* __restrict__ ws)
{
    const float* gw[5] = {Wi_w, Wf_w, Wd_w, Wg_w, Wo_w};
    const float* gb[5] = {Wi_b, Wf_b, Wd_b, Wg_b, Wo_b};
    int idx = blockIdx.x * 256 + threadIdx.x;
    if (idx < 196608) {            // W_all [r<64][col<3072]
        int r = idx / 3072, col = idx - r * 3072;
        float v;
        if (col < 512) {
            v = Wh_w[r * 512 + col] + Wh_w[(192 + r) * 512 + col]
              + Wh_w[(384 + r) * 512 + col] + Wh_w[(576 + r) * 512 + col];
        } else {
            int q = col - 512;
            int e = q / 640;
            int rem = q - e * 640;
            int g = rem >> 7, h = rem & 127;
            v = gw[g][(e * 192 + r) * 128 + h];
        }
        ws[OFF_WALL + idx] = v;
    } else if (idx < 196608 + 262144) {  // WhhE [e][j4][col][q]
        int i = idx - 196608;
        int q = i & 3;
        int col = (i >> 2) & 127;
        int j4 = (i >> 9) & 127;
        int e = i >> 16;
        int j = j4 * 4 + q;                          // j = m*128 + jj
        int row = (j >> 7) * 192 + 64 + (j & 127);
        ws[OFF_WHHP + i] = Wh_w[row * 512 + e * 128 + col];
    } else if (idx < 196608 + 262144 + 327680) { // WgE
        int i = idx - (196608 + 262144);
        int q = i & 3;
        int h = (i >> 2) & 127;
        int rest = i >> 9;        // (e*32+j4)*5+g
        int g = rest % 5;
        int ej = rest / 5;
        int e = ej >> 5, j4 = ej & 31;
        int j = j4 * 4 + q;
        ws[OFF_WGP + i] = gw[g][(e * 192 + 64 + j) * 128 + h];
    }
    if (idx < 3072) {              // bias
        float v;
        if (idx < 512) v = Wh_b[idx];
        else {
            int q = idx - 512;
            int e = q / 640;
            int rem = q - e * 640;
            int g = rem >> 7, h = rem & 127;
            v = gb[g][e * 128 + h];
        }
        ws[OFF_BIAS + idx] = v;
    }
    if (idx < 2048) {              // zero sync flags (every launch, graph-safe)
        reinterpret_cast<int*>(ws + OFF_FLAGS)[idx] = 0;
    }
}

// ---------------- K1: XG[4096][3072] = X[4096][64] @ W_all + bias ----------------
__global__ __launch_bounds__(256) void k1_xproj(
    const float* __restrict__ x, const float* wsr, float* XG)
{
    __shared__ __align__(16) float XT[64 * 68];   // [k][i], padded
    const float* W_all = wsr + OFF_WALL;
    const float* bias  = wsr + OFF_BIAS;
    int bid = blockIdx.x;
    int ct = bid % 48, rt = bid / 48;
    int r0 = rt * 64, c0 = ct * 64;
    for (int p = threadIdx.x; p < 4096; p += 256) {
        int i = p >> 6, k = p & 63;
        XT[k * 68 + i] = x[(r0 + i) * 64 + k];
    }
    __syncthreads();
    int col = c0 + (threadIdx.x & 63);
    int iq = threadIdx.x >> 6;
    float acc[16];
    #pragma unroll
    for (int r = 0; r < 16; r++) acc[r] = 0.f;
    const float* wp = W_all + col;
    #pragma unroll 4
    for (int k = 0; k < 64; k++) {
        float w = wp[k * 3072];
        const float4* xt4 = reinterpret_cast<const float4*>(&XT[k * 68 + iq * 16]);
        #pragma unroll
        for (int r4 = 0; r4 < 4; r4++) {
            float4 xv = xt4[r4];
            acc[r4 * 4 + 0] = fmaf(xv.x, w, acc[r4 * 4 + 0]);
            acc[r4 * 4 + 1] = fmaf(xv.y, w, acc[r4 * 4 + 1]);
            acc[r4 * 4 + 2] = fmaf(xv.z, w, acc[r4 * 4 + 2]);
            acc[r4 * 4 + 3] = fmaf(xv.w, w, acc[r4 * 4 + 3]);
        }
    }
    float bv = bias[col];
    #pragma unroll
    for (int r = 0; r < 16; r++) {
        int row = r0 + iq * 16 + r;
        XG[row * 3072 + col] = acc[r] + bv;
    }
}

// ---------------- K2: recurrence, 256 blocks (group of 4 = 1 batch pair) ----------------
// block -> (e, group): e = (bid>>3)&3, group = (bid&7) | ((bid>>5)<<3)
// so the 4 blocks of a group share bid%8 -> same XCD under round-robin (perf only).
__global__ __launch_bounds__(512, 2) void k2_recur(
    const float4* __restrict__ WhhE,
    const float4* __restrict__ WgE,
    const float* __restrict__ XG,
    const float* __restrict__ dt_time,
    const float* __restrict__ alpha,
    float* __restrict__ Gst,
    float* __restrict__ hbuf,
    int* __restrict__ flags,
    float* __restrict__ lam_out)
{
    __shared__ __align__(16) float hL[2][512];
    __shared__ __align__(16) float hsL[2][128];
    __shared__ float pA[2][128];
    __shared__ float ga[2][2][5][128];
    __shared__ float red[4];
    const int tid  = threadIdx.x;
    const int bid  = blockIdx.x;
    const int e    = (bid >> 3) & 3;
    const int grp  = (bid & 7) | ((bid >> 5) << 3);
    const int b0   = grp * 2;
    const int jh   = tid >> 8;          // j-half
    const int slot = (tid >> 7) & 1;    // batch slot within pair
    const int lane = tid & 127;         // col (phase A) / h' (phase B)
    const float4* wA = WhhE + e * (128 * 128) + lane;
    const float4* wB = WgE  + e * (160 * 128) + lane;
    const float av = alpha[e * 128 + lane];
    int* gflag = flags + grp * 32;
    float cst = 0.f;                    // c state (valid on tid<256)

    for (int t = 0; t < 32; ++t) {
        const int row0 = t * 128 + b0;
        float acc = 0.f;
        if (t > 0) {
            if (tid == 0) {
                int v;
                do {
                    v = __hip_atomic_load(&gflag[t - 1], __ATOMIC_ACQUIRE,
                                          __HIP_MEMORY_SCOPE_AGENT);
                    if (v < 4) __builtin_amdgcn_s_sleep(2);
                } while (v < 4);
            }
            __syncthreads();
            {   // stage h (parity t&1) -> LDS
                const float4* src = reinterpret_cast<const float4*>(
                    hbuf + (size_t)((t & 1) * 64 + grp) * 1024);
                float4* dst = reinterpret_cast<float4*>(&hL[0][0]);
                if (tid < 256) dst[tid] = src[tid];
            }
            __syncthreads();
            const float4* h4 = reinterpret_cast<const float4*>(&hL[slot][0]) + jh * 64;
            const float4* wp = wA + jh * (64 * 128);
            #pragma unroll 8
            for (int j4 = 0; j4 < 64; ++j4) {
                float4 w = wp[j4 * 128];
                float4 v = h4[j4];
                acc = fmaf(v.x, w.x, acc); acc = fmaf(v.y, w.y, acc);
                acc = fmaf(v.z, w.z, acc); acc = fmaf(v.w, w.w, acc);
            }
        } else {
            __syncthreads();  // keep barrier count uniform-ish (uniform branch anyway)
        }
        if (jh == 1) pA[slot][lane] = acc;
        __syncthreads();
        if (tid < 256) {
            float hsv = acc + pA[slot][lane]
                      + XG[(size_t)(row0 + slot) * 3072 + e * 128 + lane];
            hsL[slot][lane] = hsv;
        }
        __syncthreads();
        // phase B: 5 gate partial dots over this thread's j-half
        float g0 = 0.f, g1 = 0.f, g2 = 0.f, g3 = 0.f, g4 = 0.f;
        {
            const float4* hs4 = reinterpret_cast<const float4*>(&hsL[slot][0]) + jh * 16;
            const float4* wp  = wB + jh * (16 * 5 * 128);
            #pragma unroll 4
            for (int j4 = 0; j4 < 16; ++j4) {
                float4 v  = hs4[j4];
                float4 w0 = wp[(j4 * 5 + 0) * 128];
                float4 w1 = wp[(j4 * 5 + 1) * 128];
                float4 w2 = wp[(j4 * 5 + 2) * 128];
                float4 w3 = wp[(j4 * 5 + 3) * 128];
                float4 w4 = wp[(j4 * 5 + 4) * 128];
                g0 = fmaf(v.x, w0.x, g0); g0 = fmaf(v.y, w0.y, g0);
                g0 = fmaf(v.z, w0.z, g0); g0 = fmaf(v.w, w0.w, g0);
                g1 = fmaf(v.x, w1.x, g1); g1 = fmaf(v.y, w1.y, g1);
                g1 = fmaf(v.z, w1.z, g1); g1 = fmaf(v.w, w1.w, g1);
                g2 = fmaf(v.x, w2.x, g2); g2 = fmaf(v.y, w2.y, g2);
                g2 = fmaf(v.z, w2.z, g2); g2 = fmaf(v.w, w2.w, g2);
                g3 = fmaf(v.x, w3.x, g3); g3 = fmaf(v.y, w3.y, g3);
                g3 = fmaf(v.z, w3.z, g3); g3 = fmaf(v.w, w3.w, g3);
                g4 = fmaf(v.x, w4.x, g4); g4 = fmaf(v.y, w4.y, g4);
                g4 = fmaf(v.z, w4.z, g4); g4 = fmaf(v.w, w4.w, g4);
            }
        }
        ga[jh][slot][0][lane] = g0;
        ga[jh][slot][1][lane] = g1;
        ga[jh][slot][2][lane] = g2;
        ga[jh][slot][3][lane] = g3;
        ga[jh][slot][4][lane] = g4;
        __syncthreads();
        if (tid < 256) {
            const float* xg = XG + (size_t)(row0 + slot) * 3072 + 512 + e * 640 + lane;
            float ai = ga[0][slot][0][lane] + ga[1][slot][0][lane] + xg[0];
            float af = ga[0][slot][1][lane] + ga[1][slot][1][lane] + xg[128];
            float ad = ga[0][slot][2][lane] + ga[1][slot][2][lane] + xg[256];
            float agt = ga[0][slot][3][lane] + ga[1][slot][3][lane] + xg[384];
            float ao = ga[0][slot][4][lane] + ga[1][slot][4][lane] + xg[512];
            float ig = fast_sig(ai);
            float fg = fast_sig(af);
            float dl = __expf(ad);
            float gt = tanhf(agt);
            float og = fast_sig(ao);
            float gc = fmaf(fg, cst, ig * gt);
            float df = cst - gc;
            float dtv = dt_time[row0 + slot];
            cst = fmaf(df, __expf(-dl * dtv), gc);
            float hn = og * tanhf(cst);
            size_t go = (size_t)(row0 + slot) * 512 + e * 128 + lane;
            Gst[0 * GST_PLANE + go] = gc;
            Gst[1 * GST_PLANE + go] = df;
            Gst[2 * GST_PLANE + go] = dl;
            Gst[3 * GST_PLANE + go] = og;
            hbuf[((size_t)(((t + 1) & 1) * 64 + grp) * 2 + slot) * 512 + e * 128 + lane] = hn;
            float l = av * hn;
            #pragma unroll
            for (int off = 32; off > 0; off >>= 1) l += __shfl_down(l, off, 64);
            if ((tid & 63) == 0) red[tid >> 6] = l;
        }
        __syncthreads();
        if (tid == 0) {
            lam_out[(row0 + 0) * 4 + e] = red[0] + red[1];
            lam_out[(row0 + 1) * 4 + e] = red[2] + red[3];
            __threadfence();
            __hip_atomic_fetch_add(&gflag[t], 1, __ATOMIC_RELEASE,
                                   __HIP_MEMORY_SCOPE_AGENT);
        }
    }
}

// ---------------- K3: trapezoid integrals, 1 block per (t,b) ----------------
__global__ __launch_bounds__(256) void k3_trap(
    const float* __restrict__ Gst, const float* __restrict__ dt_time,
    const float* __restrict__ alpha, float* __restrict__ integ_out)
{
    __shared__ float red[4][2];
    const int row = blockIdx.x;          // t*128+b
    const int tid = threadIdx.x;
    const float dtv = dt_time[row];
    const int base = row * 512;
    const int pA = tid, pB = tid + 256;
    float gcA = Gst[0 * GST_PLANE + base + pA];
    float gcB = Gst[0 * GST_PLANE + base + pB];
    float dfA = Gst[1 * GST_PLANE + base + pA];
    float dfB = Gst[1 * GST_PLANE + base + pB];
    float dlA = Gst[2 * GST_PLANE + base + pA];
    float dlB = Gst[2 * GST_PLANE + base + pB];
    float oA  = Gst[3 * GST_PLANE + base + pA];
    float oB  = Gst[3 * GST_PLANE + base + pB];
    float aoA = alpha[pA] * oA;
    float aoB = alpha[pB] * oB;
    float g2A = 2.f * gcA, d2A = 2.f * dfA;
    float g2B = 2.f * gcB, d2B = 2.f * dfB;
    float qA = dlA * dtv, qB = dlB * dtv;
    float rA = __expf(-qA * 0.01f);
    float rB = __expf(-qB * 0.01f);
    float E100A = __expf(-qA);
    float E100B = __expf(-qB);
    float sA = 0.5f * (__fdividef(1.f, __expf(g2A + d2A) + 1.f)
                     + __fdividef(1.f, __expf(fmaf(d2A, E100A, g2A)) + 1.f));
    float sB = 0.5f * (__fdividef(1.f, __expf(g2B + d2B) + 1.f)
                     + __fdividef(1.f, __expf(fmaf(d2B, E100B, g2B)) + 1.f));
    float EA = rA, EB = rB;
    for (int k = 1; k < 100; k++) {
        sA += __fdividef(1.f, __expf(fmaf(d2A, EA, g2A)) + 1.f);
        sB += __fdividef(1.f, __expf(fmaf(d2B, EB, g2B)) + 1.f);
        EA *= rA;
        EB *= rB;
    }
    float vA = aoA * (100.f - 2.f * sA);
    float vB = aoB * (100.f - 2.f * sB);
    #pragma unroll
    for (int off = 32; off > 0; off >>= 1) {
        vA += __shfl_down(vA, off, 64);
        vB += __shfl_down(vB, off, 64);
    }
    const int wv = tid >> 6;
    if ((tid & 63) == 0) { red[wv][0] = vA; red[wv][1] = vB; }
    __syncthreads();
    if (tid < 4) {
        float v = (tid < 2) ? (red[2 * tid][0] + red[2 * tid + 1][0])
                            : (red[2 * (tid - 2)][1] + red[2 * (tid - 2) + 1][1]);
        integ_out[row * 4 + tid] = v * (dtv * 0.01f);
    }
}

extern "C" void kernel_launch(void* const* d_in, const int* in_sizes, int n_in,
                              void* d_out, int out_size, void* d_ws, size_t ws_size,
                              hipStream_t stream)
{
    const float* x_time  = (const float*)d_in[0];
    const float* dt_time = (const float*)d_in[1];
    const float* Wh_w = (const float*)d_in[2];
    const float* Wh_b = (const float*)d_in[3];
    const float* Wi_w = (const float*)d_in[4];
    const float* Wi_b = (const float*)d_in[5];
    const float* Wf_w = (const float*)d_in[6];
    const float* Wf_b = (const float*)d_in[7];
    const float* Wd_w = (const float*)d_in[8];
    const float* Wd_b = (const float*)d_in[9];
    const float* Wg_w = (const float*)d_in[10];
    const float* Wg_b = (const float*)d_in[11];
    const float* Wo_w = (const float*)d_in[12];
    const float* Wo_b = (const float*)d_in[13];
    const float* alpha = (const float*)d_in[14];

    float* ws = (float*)d_ws;
    float* XG   = ws + OFF_XG;
    float* Gst  = ws + OFF_GST;
    float* hbuf = ws + OFF_HBUF;
    int*   flags = (int*)(ws + OFF_FLAGS);
    float* lam_out   = (float*)d_out;
    float* integ_out = lam_out + 32 * 128 * 4;

    k0_pack<<<3072, 256, 0, stream>>>(Wh_w, Wh_b, Wi_w, Wi_b, Wf_w, Wf_b,
                                      Wd_w, Wd_b, Wg_w, Wg_b, Wo_w, Wo_b, ws);
    k1_xproj<<<3072, 256, 0, stream>>>(x_time, ws, XG);
    k2_recur<<<256, 512, 0, stream>>>(
        (const float4*)(ws + OFF_WHHP), (const float4*)(ws + OFF_WGP),
        XG, dt_time, alpha, Gst, hbuf, flags, lam_out);
    k3_trap<<<4096, 256, 0, stream>>>(Gst, dt_time, alpha, integ_out);
}

// Round 3
// 434.729 us; speedup vs baseline: 1.9972x; 1.7885x over previous
//
#include <hip/hip_runtime.h>

// stackCLSTM: T=32, B=128, I=64, H=128, E=4, N_TRAP=100
// ws layout (float-word offsets):
//   W_all  [64][3072] fp32        @ 0         (196608)
//   bias   [3072] fp32            @ 196608    (3072)
//   WhhH   [e][kq][64][128] u32   @ 199680    (131072)  fp16-pair packed Whh h-part
//   WgH    [e][kq][16][5][128] u32@ 330752    (163840)  fp16-pair packed gate h-part
//   XG     [4096][3072] fp32      @ 494592    (12582912)
//   Gst    [4][4096*512] fp32     @ 13077504  (8388608)
//   hbuf   [2][64][4][2][64] u32  @ 21466112  (65536)   fp16-pair packed h state
//   flags  [64][32] int           @ 21531648  (2048)
#define OFF_WALL   0
#define OFF_BIAS   196608
#define OFF_WHHH   199680
#define OFF_WGH    330752
#define OFF_XG     494592
#define OFF_GST    13077504
#define OFF_HBUF   21466112
#define OFF_FLAGS  21531648
#define GST_PLANE  2097152

typedef _Float16 half2_t __attribute__((ext_vector_type(2)));

__device__ __forceinline__ float fast_sig(float x) {
    return __fdividef(1.f, 1.f + __expf(-x));
}
__device__ __forceinline__ unsigned pack2h(float a, float b) {
    _Float16 ha = (_Float16)a, hb = (_Float16)b;
    unsigned short ua = __builtin_bit_cast(unsigned short, ha);
    unsigned short ub = __builtin_bit_cast(unsigned short, hb);
    return ((unsigned)ub << 16) | ua;
}
__device__ __forceinline__ float dot2(unsigned w, unsigned h, float acc) {
    return __builtin_amdgcn_fdot2(__builtin_bit_cast(half2_t, w),
                                  __builtin_bit_cast(half2_t, h), acc, false);
}

// ---------------- K0: pack weights (fp32 W_all + fp16 h-part) + zero flags ----------------
__global__ __launch_bounds__(256) void k0_pack(
    const float* __restrict__ Wh_w, const float* __restrict__ Wh_b,
    const float* __restrict__ Wi_w, const float* __restrict__ Wi_b,
    const float* __restrict__ Wf_w, const float* __restrict__ Wf_b,
    const float* __restrict__ Wd_w, const float* __restrict__ Wd_b,
    const float* __restrict__ Wg_w, const float* __restrict__ Wg_b,
    const float* __restrict__ Wo_w, const float* __restrict__ Wo_b,
    float* __restrict__ ws)
{
    const float* gw[5] = {Wi_w, Wf_w, Wd_w, Wg_w, Wo_w};
    const float* gb[5] = {Wi_b, Wf_b, Wd_b, Wg_b, Wo_b};
    int idx = blockIdx.x * 256 + threadIdx.x;
    if (idx < 196608) {            // W_all [r<64][col<3072]
        int r = idx / 3072, col = idx - r * 3072;
        float v;
        if (col < 512) {
            v = Wh_w[r * 512 + col] + Wh_w[(192 + r) * 512 + col]
              + Wh_w[(384 + r) * 512 + col] + Wh_w[(576 + r) * 512 + col];
        } else {
            int q = col - 512;
            int e = q / 640;
            int rem = q - e * 640;
            int g = rem >> 7, h = rem & 127;
            v = gw[g][(e * 192 + r) * 128 + h];
        }
        ws[OFF_WALL + idx] = v;
    } else if (idx < 327680) {     // WhhH [e][kq][64 ii][128 lane] packed pairs
        int i = idx - 196608;
        int lane = i & 127;
        int ii = (i >> 7) & 63;
        int kq = (i >> 13) & 3;
        int e  = i >> 15;
        int k0 = kq * 128 + 2 * ii, k1 = k0 + 1;
        int r0 = (k0 >> 7) * 192 + 64 + (k0 & 127);
        int r1 = (k1 >> 7) * 192 + 64 + (k1 & 127);
        float w0 = Wh_w[r0 * 512 + e * 128 + lane];
        float w1 = Wh_w[r1 * 512 + e * 128 + lane];
        reinterpret_cast<unsigned*>(ws + OFF_WHHH)[i] = pack2h(w0, w1);
    } else if (idx < 491520) {     // WgH [e][kq][16 ii][5 g][128 lane]
        int i = idx - 327680;
        int lane = i & 127;
        int gg = (i >> 7) % 5;
        int rest = (i >> 7) / 5;
        int ii = rest & 15;
        int kq = (rest >> 4) & 3;
        int e  = rest >> 6;
        int k0 = kq * 32 + 2 * ii, k1 = k0 + 1;
        float w0 = gw[gg][(e * 192 + 64 + k0) * 128 + lane];
        float w1 = gw[gg][(e * 192 + 64 + k1) * 128 + lane];
        reinterpret_cast<unsigned*>(ws + OFF_WGH)[i] = pack2h(w0, w1);
    }
    if (idx < 3072) {              // bias
        float v;
        if (idx < 512) v = Wh_b[idx];
        else {
            int q = idx - 512;
            int e = q / 640;
            int rem = q - e * 640;
            int g = rem >> 7, h = rem & 127;
            v = gb[g][e * 128 + h];
        }
        ws[OFF_BIAS + idx] = v;
    }
    if (idx < 2048) {              // zero sync flags every launch (graph-safe)
        reinterpret_cast<int*>(ws + OFF_FLAGS)[idx] = 0;
    }
}

// ---------------- K1: XG[4096][3072] = X[4096][64] @ W_all + bias ----------------
__global__ __launch_bounds__(256) void k1_xproj(
    const float* __restrict__ x, const float* wsr, float* XG)
{
    __shared__ __align__(16) float XT[64 * 68];
    const float* W_all = wsr + OFF_WALL;
    const float* bias  = wsr + OFF_BIAS;
    int bid = blockIdx.x;
    int ct = bid % 48, rt = bid / 48;
    int r0 = rt * 64, c0 = ct * 64;
    for (int p = threadIdx.x; p < 4096; p += 256) {
        int i = p >> 6, k = p & 63;
        XT[k * 68 + i] = x[(r0 + i) * 64 + k];
    }
    __syncthreads();
    int col = c0 + (threadIdx.x & 63);
    int iq = threadIdx.x >> 6;
    float acc[16];
    #pragma unroll
    for (int r = 0; r < 16; r++) acc[r] = 0.f;
    const float* wp = W_all + col;
    #pragma unroll 4
    for (int k = 0; k < 64; k++) {
        float w = wp[k * 3072];
        const float4* xt4 = reinterpret_cast<const float4*>(&XT[k * 68 + iq * 16]);
        #pragma unroll
        for (int r4 = 0; r4 < 4; r4++) {
            float4 xv = xt4[r4];
            acc[r4 * 4 + 0] = fmaf(xv.x, w, acc[r4 * 4 + 0]);
            acc[r4 * 4 + 1] = fmaf(xv.y, w, acc[r4 * 4 + 1]);
            acc[r4 * 4 + 2] = fmaf(xv.z, w, acc[r4 * 4 + 2]);
            acc[r4 * 4 + 3] = fmaf(xv.w, w, acc[r4 * 4 + 3]);
        }
    }
    float bv = bias[col];
    #pragma unroll
    for (int r = 0; r < 16; r++) {
        int row = r0 + iq * 16 + r;
        XG[row * 3072 + col] = acc[r] + bv;
    }
}

// ---------------- K2: recurrence, register-resident fp16 weights ----------------
// 256 blocks; group of 4 (one per e) = 1 batch pair. K-dim split 4-way (kq=tid>>7).
__global__ __launch_bounds__(512, 2) void k2_recur(
    const unsigned* __restrict__ WhhH,
    const unsigned* __restrict__ WgH,
    const float* __restrict__ XG,
    const float* __restrict__ dt_time,
    const float* __restrict__ alpha,
    float* __restrict__ Gst,
    unsigned* __restrict__ hbuf,
    int* __restrict__ flags,
    float* __restrict__ lam_out)
{
    __shared__ __align__(16) unsigned hL[256][2];   // [pair p=e*64+j/2][slot]
    __shared__ __align__(16) float hsF[2][128];
    __shared__ float pA[4][2][128];
    __shared__ float pB[4][2][5][128];
    __shared__ float red[4];
    const int tid = threadIdx.x;
    const int bid = blockIdx.x;
    const int e   = (bid >> 3) & 3;
    const int grp = (bid & 7) | ((bid >> 5) << 3);
    const int b0  = grp * 2;
    const int kq  = tid >> 7;          // K-quarter
    const int lane = tid & 127;        // output index (col / h')
    const int s = (tid >> 7) & 1, l = lane;   // roles for tid<256

    // --- load weights into registers (once) ---
    unsigned wa[64];
    #pragma unroll
    for (int i = 0; i < 64; i++)
        wa[i] = WhhH[((e * 4 + kq) * 64 + i) * 128 + lane];
    unsigned wg[5][16];
    #pragma unroll
    for (int i = 0; i < 16; i++) {
        #pragma unroll
        for (int g = 0; g < 5; g++)
            wg[g][i] = WgH[(((e * 4 + kq) * 16 + i) * 5 + g) * 128 + lane];
    }
    const float av = alpha[e * 128 + lane];
    int* gflag = flags + grp * 32;
    float cst = 0.f;

    for (int t = 0; t < 32; ++t) {
        const int row0 = t * 128 + b0;
        // (1) prefetch this step's XG slice (independent of other blocks)
        float xg0 = 0.f, xgg0 = 0.f, xgg1 = 0.f, xgg2 = 0.f, xgg3 = 0.f, xgg4 = 0.f;
        if (tid < 256) {
            const float* base = XG + (size_t)(row0 + s) * 3072;
            xg0 = base[e * 128 + l];
            const float* gp = base + 512 + e * 640 + l;
            xgg0 = gp[0]; xgg1 = gp[128]; xgg2 = gp[256]; xgg3 = gp[384]; xgg4 = gp[512];
        }
        if (t > 0) {
            // (2) wait for group step t-1
            if (tid == 0) {
                int v;
                do {
                    v = __hip_atomic_load(&gflag[t - 1], __ATOMIC_RELAXED,
                                          __HIP_MEMORY_SCOPE_AGENT);
                    if (v < 4) __builtin_amdgcn_s_sleep(2);
                } while (v < 4);
                (void)__hip_atomic_load(&gflag[t - 1], __ATOMIC_ACQUIRE,
                                        __HIP_MEMORY_SCOPE_AGENT);
            }
            __syncthreads();
            // (3) stage h (parity t&1) -> LDS, 512 u32 coalesced
            {
                const unsigned* src = hbuf + (size_t)((t & 1) * 64 + grp) * 512;
                int eh = tid >> 7, sh = (tid >> 6) & 1, p = tid & 63;
                hL[eh * 64 + p][sh] = src[tid];
            }
            __syncthreads();
            // (4) phase A: partial hs dots over K-quarter
            float a0 = 0.f, a1 = 0.f;
            #pragma unroll
            for (int i = 0; i < 64; i++) {
                uint2 hp = *reinterpret_cast<const uint2*>(&hL[kq * 64 + i][0]);
                a0 = dot2(wa[i], hp.x, a0);
                a1 = dot2(wa[i], hp.y, a1);
            }
            pA[kq][0][lane] = a0;
            pA[kq][1][lane] = a1;
            __syncthreads();
            if (tid < 256) {
                float hs = pA[0][s][l] + pA[1][s][l] + pA[2][s][l] + pA[3][s][l] + xg0;
                hsF[s][l] = hs;
            }
        } else {
            if (tid < 256) hsF[s][l] = xg0;   // h=0 at t=0
        }
        __syncthreads();
        // (5) phase B: 5 gate partial dots over K-quarter (K=128)
        float b0a = 0.f, b1a = 0.f, b2a = 0.f, b3a = 0.f, b4a = 0.f;
        float b0b = 0.f, b1b = 0.f, b2b = 0.f, b3b = 0.f, b4b = 0.f;
        #pragma unroll
        for (int i = 0; i < 16; i++) {
            float2 f0 = *reinterpret_cast<const float2*>(&hsF[0][kq * 32 + 2 * i]);
            float2 f1 = *reinterpret_cast<const float2*>(&hsF[1][kq * 32 + 2 * i]);
            unsigned h0 = pack2h(f0.x, f0.y);
            unsigned h1 = pack2h(f1.x, f1.y);
            b0a = dot2(wg[0][i], h0, b0a); b0b = dot2(wg[0][i], h1, b0b);
            b1a = dot2(wg[1][i], h0, b1a); b1b = dot2(wg[1][i], h1, b1b);
            b2a = dot2(wg[2][i], h0, b2a); b2b = dot2(wg[2][i], h1, b2b);
            b3a = dot2(wg[3][i], h0, b3a); b3b = dot2(wg[3][i], h1, b3b);
            b4a = dot2(wg[4][i], h0, b4a); b4b = dot2(wg[4][i], h1, b4b);
        }
        pB[kq][0][0][lane] = b0a; pB[kq][0][1][lane] = b1a; pB[kq][0][2][lane] = b2a;
        pB[kq][0][3][lane] = b3a; pB[kq][0][4][lane] = b4a;
        pB[kq][1][0][lane] = b0b; pB[kq][1][1][lane] = b1b; pB[kq][1][2][lane] = b2b;
        pB[kq][1][3][lane] = b3b; pB[kq][1][4][lane] = b4b;
        __syncthreads();
        // (6) cell update + outputs (tid<256: s,l)
        if (tid < 256) {
            float ai = pB[0][s][0][l] + pB[1][s][0][l] + pB[2][s][0][l] + pB[3][s][0][l] + xgg0;
            float af = pB[0][s][1][l] + pB[1][s][1][l] + pB[2][s][1][l] + pB[3][s][1][l] + xgg1;
            float ad = pB[0][s][2][l] + pB[1][s][2][l] + pB[2][s][2][l] + pB[3][s][2][l] + xgg2;
            float ag = pB[0][s][3][l] + pB[1][s][3][l] + pB[2][s][3][l] + pB[3][s][3][l] + xgg3;
            float ao = pB[0][s][4][l] + pB[1][s][4][l] + pB[2][s][4][l] + pB[3][s][4][l] + xgg4;
            float ig = fast_sig(ai);
            float fg = fast_sig(af);
            float dl = __expf(ad);
            float gt = tanhf(ag);
            float og = fast_sig(ao);
            float gc = fmaf(fg, cst, ig * gt);
            float df = cst - gc;
            float dtv = dt_time[row0 + s];
            cst = fmaf(df, __expf(-dl * dtv), gc);
            float hn = og * tanhf(cst);
            size_t go = (size_t)(row0 + s) * 512 + e * 128 + l;
            Gst[0 * GST_PLANE + go] = gc;
            Gst[1 * GST_PLANE + go] = df;
            Gst[2 * GST_PLANE + go] = dl;
            Gst[3 * GST_PLANE + go] = og;
            // pack h_new pairs (lanes 2p,2p+1 within same wave) -> hbuf parity (t+1)&1
            float hi = __shfl_down(hn, 1, 64);
            if ((l & 1) == 0) {
                hbuf[(size_t)(((t + 1) & 1) * 64 + grp) * 512 + (e * 2 + s) * 64 + (l >> 1)]
                    = pack2h(hn, hi);
            }
            // lambda reduce
            float lm = av * hn;
            #pragma unroll
            for (int off = 32; off > 0; off >>= 1) lm += __shfl_down(lm, off, 64);
            if ((tid & 63) == 0) red[tid >> 6] = lm;
        }
        __syncthreads();
        if (tid == 0) {
            lam_out[(row0 + 0) * 4 + e] = red[0] + red[1];
            lam_out[(row0 + 1) * 4 + e] = red[2] + red[3];
            __hip_atomic_fetch_add(&gflag[t], 1, __ATOMIC_RELEASE,
                                   __HIP_MEMORY_SCOPE_AGENT);
        }
    }
}

// ---------------- K3: trapezoid integrals, 1 block per (t,b) ----------------
__global__ __launch_bounds__(256) void k3_trap(
    const float* __restrict__ Gst, const float* __restrict__ dt_time,
    const float* __restrict__ alpha, float* __restrict__ integ_out)
{
    __shared__ float red[4][2];
    const int row = blockIdx.x;
    const int tid = threadIdx.x;
    const float dtv = dt_time[row];
    const int base = row * 512;
    const int pA = tid, pB = tid + 256;
    float gcA = Gst[0 * GST_PLANE + base + pA];
    float gcB = Gst[0 * GST_PLANE + base + pB];
    float dfA = Gst[1 * GST_PLANE + base + pA];
    float dfB = Gst[1 * GST_PLANE + base + pB];
    float dlA = Gst[2 * GST_PLANE + base + pA];
    float dlB = Gst[2 * GST_PLANE + base + pB];
    float oA  = Gst[3 * GST_PLANE + base + pA];
    float oB  = Gst[3 * GST_PLANE + base + pB];
    float aoA = alpha[pA] * oA;
    float aoB = alpha[pB] * oB;
    float g2A = 2.f * gcA, d2A = 2.f * dfA;
    float g2B = 2.f * gcB, d2B = 2.f * dfB;
    float qA = dlA * dtv, qB = dlB * dtv;
    float rA = __expf(-qA * 0.01f);
    float rB = __expf(-qB * 0.01f);
    float E100A = __expf(-qA);
    float E100B = __expf(-qB);
    float sA = 0.5f * (__fdividef(1.f, __expf(g2A + d2A) + 1.f)
                     + __fdividef(1.f, __expf(fmaf(d2A, E100A, g2A)) + 1.f));
    float sB = 0.5f * (__fdividef(1.f, __expf(g2B + d2B) + 1.f)
                     + __fdividef(1.f, __expf(fmaf(d2B, E100B, g2B)) + 1.f));
    float EA = rA, EB = rB;
    for (int k = 1; k < 100; k++) {
        sA += __fdividef(1.f, __expf(fmaf(d2A, EA, g2A)) + 1.f);
        sB += __fdividef(1.f, __expf(fmaf(d2B, EB, g2B)) + 1.f);
        EA *= rA;
        EB *= rB;
    }
    float vA = aoA * (100.f - 2.f * sA);
    float vB = aoB * (100.f - 2.f * sB);
    #pragma unroll
    for (int off = 32; off > 0; off >>= 1) {
        vA += __shfl_down(vA, off, 64);
        vB += __shfl_down(vB, off, 64);
    }
    const int wv = tid >> 6;
    if ((tid & 63) == 0) { red[wv][0] = vA; red[wv][1] = vB; }
    __syncthreads();
    if (tid < 4) {
        float v = (tid < 2) ? (red[2 * tid][0] + red[2 * tid + 1][0])
                            : (red[2 * (tid - 2)][1] + red[2 * (tid - 2) + 1][1]);
        integ_out[row * 4 + tid] = v * (dtv * 0.01f);
    }
}

extern "C" void kernel_launch(void* const* d_in, const int* in_sizes, int n_in,
                              void* d_out, int out_size, void* d_ws, size_t ws_size,
                              hipStream_t stream)
{
    const float* x_time  = (const float*)d_in[0];
    const float* dt_time = (const float*)d_in[1];
    const float* Wh_w = (const float*)d_in[2];
    const float* Wh_b = (const float*)d_in[3];
    const float* Wi_w = (const float*)d_in[4];
    const float* Wi_b = (const float*)d_in[5];
    const float* Wf_w = (const float*)d_in[6];
    const float* Wf_b = (const float*)d_in[7];
    const float* Wd_w = (const float*)d_in[8];
    const float* Wd_b = (const float*)d_in[9];
    const float* Wg_w = (const float*)d_in[10];
    const float* Wg_b = (const float*)d_in[11];
    const float* Wo_w = (const float*)d_in[12];
    const float* Wo_b = (const float*)d_in[13];
    const float* alpha = (const float*)d_in[14];

    float* ws = (float*)d_ws;
    float* XG   = ws + OFF_XG;
    float* Gst  = ws + OFF_GST;
    unsigned* hbuf = (unsigned*)(ws + OFF_HBUF);
    int*   flags = (int*)(ws + OFF_FLAGS);
    float* lam_out   = (float*)d_out;
    float* integ_out = lam_out + 32 * 128 * 4;

    k0_pack<<<3072, 256, 0, stream>>>(Wh_w, Wh_b, Wi_w, Wi_b, Wf_w, Wf_b,
                                      Wd_w, Wd_b, Wg_w, Wg_b, Wo_w, Wo_b, ws);
    k1_xproj<<<3072, 256, 0, stream>>>(x_time, ws, XG);
    k2_recur<<<256, 512, 0, stream>>>(
        (const unsigned*)(ws + OFF_WHHH), (const unsigned*)(ws + OFF_WGH),
        XG, dt_time, alpha, Gst, hbuf, flags, lam_out);
    k3_trap<<<4096, 256, 0, stream>>>(Gst, dt_time, alpha, integ_out);
}

// Round 4
// 269.404 us; speedup vs baseline: 3.2228x; 1.6137x over previous
//
#include <hip/hip_runtime.h>

// stackCLSTM: T=32, B=128, I=64, H=128, E=4, N_TRAP=100
// ws layout (float-word offsets):
//   W_all  [64][3072] fp32        @ 0         (196608)
//   bias   [3072] fp32            @ 196608    (3072)
//   WhhH   [e][kq][64][128] u32   @ 199680    (131072)  fp16-pair packed Whh h-part
//   WgH    [e][kq][16][5][128] u32@ 330752    (163840)  fp16-pair packed gate h-part
//   XG     [4096][3072] fp32      @ 494592    (12582912)
//   Gst    [4][4096*512] fp32     @ 13077504  (8388608)
//   hbuf   [2][64][4][2][64] u32  @ 21466112  (65536)   fp16-pair packed h state
//   flags  [64][32] int           @ 21531648  (2048)
#define OFF_WALL   0
#define OFF_BIAS   196608
#define OFF_WHHH   199680
#define OFF_WGH    330752
#define OFF_XG     494592
#define OFF_GST    13077504
#define OFF_HBUF   21466112
#define OFF_FLAGS  21531648
#define GST_PLANE  2097152

typedef _Float16 half2_t __attribute__((ext_vector_type(2)));

__device__ __forceinline__ float fast_sig(float x) {
    return __fdividef(1.f, 1.f + __expf(-x));
}
__device__ __forceinline__ unsigned pack2h(float a, float b) {
    _Float16 ha = (_Float16)a, hb = (_Float16)b;
    unsigned short ua = __builtin_bit_cast(unsigned short, ha);
    unsigned short ub = __builtin_bit_cast(unsigned short, hb);
    return ((unsigned)ub << 16) | ua;
}
__device__ __forceinline__ float dot2(unsigned w, unsigned h, float acc) {
    return __builtin_amdgcn_fdot2(__builtin_bit_cast(half2_t, w),
                                  __builtin_bit_cast(half2_t, h), acc, false);
}

// ---------------- K0: pack weights (fp32 W_all + fp16 h-part) + zero flags ----------------
__global__ __launch_bounds__(256) void k0_pack(
    const float* __restrict__ Wh_w, const float* __restrict__ Wh_b,
    const float* __restrict__ Wi_w, const float* __restrict__ Wi_b,
    const float* __restrict__ Wf_w, const float* __restrict__ Wf_b,
    const float* __restrict__ Wd_w, const float* __restrict__ Wd_b,
    const float* __restrict__ Wg_w, const float* __restrict__ Wg_b,
    const float* __restrict__ Wo_w, const float* __restrict__ Wo_b,
    float* __restrict__ ws)
{
    const float* gw[5] = {Wi_w, Wf_w, Wd_w, Wg_w, Wo_w};
    const float* gb[5] = {Wi_b, Wf_b, Wd_b, Wg_b, Wo_b};
    int idx = blockIdx.x * 256 + threadIdx.x;
    if (idx < 196608) {            // W_all [r<64][col<3072]
        int r = idx / 3072, col = idx - r * 3072;
        float v;
        if (col < 512) {
            v = Wh_w[r * 512 + col] + Wh_w[(192 + r) * 512 + col]
              + Wh_w[(384 + r) * 512 + col] + Wh_w[(576 + r) * 512 + col];
        } else {
            int q = col - 512;
            int e = q / 640;
            int rem = q - e * 640;
            int g = rem >> 7, h = rem & 127;
            v = gw[g][(e * 192 + r) * 128 + h];
        }
        ws[OFF_WALL + idx] = v;
    } else if (idx < 327680) {     // WhhH [e][kq][64 ii][128 lane] packed pairs
        int i = idx - 196608;
        int lane = i & 127;
        int ii = (i >> 7) & 63;
        int kq = (i >> 13) & 3;
        int e  = i >> 15;
        int k0 = kq * 128 + 2 * ii, k1 = k0 + 1;
        int r0 = (k0 >> 7) * 192 + 64 + (k0 & 127);
        int r1 = (k1 >> 7) * 192 + 64 + (k1 & 127);
        float w0 = Wh_w[r0 * 512 + e * 128 + lane];
        float w1 = Wh_w[r1 * 512 + e * 128 + lane];
        reinterpret_cast<unsigned*>(ws + OFF_WHHH)[i] = pack2h(w0, w1);
    } else if (idx < 491520) {     // WgH [e][kq][16 ii][5 g][128 lane]
        int i = idx - 327680;
        int lane = i & 127;
        int gg = (i >> 7) % 5;
        int rest = (i >> 7) / 5;
        int ii = rest & 15;
        int kq = (rest >> 4) & 3;
        int e  = rest >> 6;
        int k0 = kq * 32 + 2 * ii, k1 = k0 + 1;
        float w0 = gw[gg][(e * 192 + 64 + k0) * 128 + lane];
        float w1 = gw[gg][(e * 192 + 64 + k1) * 128 + lane];
        reinterpret_cast<unsigned*>(ws + OFF_WGH)[i] = pack2h(w0, w1);
    }
    if (idx < 3072) {              // bias
        float v;
        if (idx < 512) v = Wh_b[idx];
        else {
            int q = idx - 512;
            int e = q / 640;
            int rem = q - e * 640;
            int g = rem >> 7, h = rem & 127;
            v = gb[g][e * 128 + h];
        }
        ws[OFF_BIAS + idx] = v;
    }
    if (idx < 2048) {              // zero sync flags every launch (graph-safe)
        reinterpret_cast<int*>(ws + OFF_FLAGS)[idx] = 0;
    }
}

// ---------------- K1: XG[4096][3072] = X[4096][64] @ W_all + bias ----------------
__global__ __launch_bounds__(256) void k1_xproj(
    const float* __restrict__ x, const float* wsr, float* XG)
{
    __shared__ __align__(16) float XT[64 * 68];
    const float* W_all = wsr + OFF_WALL;
    const float* bias  = wsr + OFF_BIAS;
    int bid = blockIdx.x;
    int ct = bid % 48, rt = bid / 48;
    int r0 = rt * 64, c0 = ct * 64;
    for (int p = threadIdx.x; p < 4096; p += 256) {
        int i = p >> 6, k = p & 63;
        XT[k * 68 + i] = x[(r0 + i) * 64 + k];
    }
    __syncthreads();
    int col = c0 + (threadIdx.x & 63);
    int iq = threadIdx.x >> 6;
    float acc[16];
    #pragma unroll
    for (int r = 0; r < 16; r++) acc[r] = 0.f;
    const float* wp = W_all + col;
    #pragma unroll 4
    for (int k = 0; k < 64; k++) {
        float w = wp[k * 3072];
        const float4* xt4 = reinterpret_cast<const float4*>(&XT[k * 68 + iq * 16]);
        #pragma unroll
        for (int r4 = 0; r4 < 4; r4++) {
            float4 xv = xt4[r4];
            acc[r4 * 4 + 0] = fmaf(xv.x, w, acc[r4 * 4 + 0]);
            acc[r4 * 4 + 1] = fmaf(xv.y, w, acc[r4 * 4 + 1]);
            acc[r4 * 4 + 2] = fmaf(xv.z, w, acc[r4 * 4 + 2]);
            acc[r4 * 4 + 3] = fmaf(xv.w, w, acc[r4 * 4 + 3]);
        }
    }
    float bv = bias[col];
    #pragma unroll
    for (int r = 0; r < 16; r++) {
        int row = r0 + iq * 16 + r;
        XG[row * 3072 + col] = acc[r] + bv;
    }
}

// ---------------- K2: recurrence, register-resident fp16 weights ----------------
// 256 blocks; group of 4 (one per e) = 1 batch pair. K-dim split 4-way (kq=tid>>7).
// Sync uses ONLY relaxed agent-scope atomics (IC-resident), no acquire/release
// cache maintenance: h data is exchanged via sc-flagged atomic ld/st that hit the
// coherence point directly; ordering store->flag is enforced by the vmcnt(0) drain
// inside __syncthreads before tid0's flag add.
__global__ __launch_bounds__(512, 2) void k2_recur(
    const unsigned* __restrict__ WhhH,
    const unsigned* __restrict__ WgH,
    const float* __restrict__ XG,
    const float* __restrict__ dt_time,
    const float* __restrict__ alpha,
    float* __restrict__ Gst,
    unsigned* __restrict__ hbuf,
    int* __restrict__ flags,
    float* __restrict__ lam_out)
{
    __shared__ __align__(16) unsigned hL[256][2];   // [pair p=e*64+j/2][slot]
    __shared__ __align__(16) float hsF[2][128];
    __shared__ float pA[4][2][128];
    __shared__ float pB[4][2][5][128];
    __shared__ float red[4];
    const int tid = threadIdx.x;
    const int bid = blockIdx.x;
    const int e   = (bid >> 3) & 3;
    const int grp = (bid & 7) | ((bid >> 5) << 3);
    const int b0  = grp * 2;
    const int kq  = tid >> 7;          // K-quarter
    const int lane = tid & 127;        // output index (col / h')
    const int s = (tid >> 7) & 1, l = lane;   // roles for tid<256

    // --- load weights into registers (once) ---
    unsigned wa[64];
    #pragma unroll
    for (int i = 0; i < 64; i++)
        wa[i] = WhhH[((e * 4 + kq) * 64 + i) * 128 + lane];
    unsigned wg[5][16];
    #pragma unroll
    for (int i = 0; i < 16; i++) {
        #pragma unroll
        for (int g = 0; g < 5; g++)
            wg[g][i] = WgH[(((e * 4 + kq) * 16 + i) * 5 + g) * 128 + lane];
    }
    const float av = alpha[e * 128 + lane];
    int* gflag = flags + grp * 32;
    float cst = 0.f;

    for (int t = 0; t < 32; ++t) {
        const int row0 = t * 128 + b0;
        // (1) prefetch this step's XG slice (issued before the wait)
        float xg0 = 0.f, xgg0 = 0.f, xgg1 = 0.f, xgg2 = 0.f, xgg3 = 0.f, xgg4 = 0.f;
        if (tid < 256) {
            const float* base = XG + (size_t)(row0 + s) * 3072;
            xg0 = base[e * 128 + l];
            const float* gp = base + 512 + e * 640 + l;
            xgg0 = gp[0]; xgg1 = gp[128]; xgg2 = gp[256]; xgg3 = gp[384]; xgg4 = gp[512];
        }
        if (t > 0) {
            // (2) wait for group step t-1 (relaxed poll, no cache maintenance)
            if (tid == 0) {
                while (__hip_atomic_load(&gflag[t - 1], __ATOMIC_RELAXED,
                                         __HIP_MEMORY_SCOPE_AGENT) < 4)
                    __builtin_amdgcn_s_sleep(1);
            }
            __syncthreads();
            asm volatile("" ::: "memory");
            // (3) stage h (parity t&1) -> LDS via IC-direct relaxed atomic loads
            {
                const unsigned* src = hbuf + (size_t)((t & 1) * 64 + grp) * 512;
                unsigned v = __hip_atomic_load(&src[tid], __ATOMIC_RELAXED,
                                               __HIP_MEMORY_SCOPE_AGENT);
                int eh = tid >> 7, sh = (tid >> 6) & 1, p = tid & 63;
                hL[eh * 64 + p][sh] = v;
            }
            __syncthreads();
            // (4) phase A: partial hs dots over K-quarter
            float a0 = 0.f, a1 = 0.f;
            #pragma unroll
            for (int i = 0; i < 64; i++) {
                uint2 hp = *reinterpret_cast<const uint2*>(&hL[kq * 64 + i][0]);
                a0 = dot2(wa[i], hp.x, a0);
                a1 = dot2(wa[i], hp.y, a1);
            }
            pA[kq][0][lane] = a0;
            pA[kq][1][lane] = a1;
            __syncthreads();
            if (tid < 256) {
                float hs = pA[0][s][l] + pA[1][s][l] + pA[2][s][l] + pA[3][s][l] + xg0;
                hsF[s][l] = hs;
            }
        } else {
            if (tid < 256) hsF[s][l] = xg0;   // h=0 at t=0
        }
        __syncthreads();
        // (5) phase B: 5 gate partial dots over K-quarter (K=128)
        float b0a = 0.f, b1a = 0.f, b2a = 0.f, b3a = 0.f, b4a = 0.f;
        float b0b = 0.f, b1b = 0.f, b2b = 0.f, b3b = 0.f, b4b = 0.f;
        #pragma unroll
        for (int i = 0; i < 16; i++) {
            float2 f0 = *reinterpret_cast<const float2*>(&hsF[0][kq * 32 + 2 * i]);
            float2 f1 = *reinterpret_cast<const float2*>(&hsF[1][kq * 32 + 2 * i]);
            unsigned h0 = pack2h(f0.x, f0.y);
            unsigned h1 = pack2h(f1.x, f1.y);
            b0a = dot2(wg[0][i], h0, b0a); b0b = dot2(wg[0][i], h1, b0b);
            b1a = dot2(wg[1][i], h0, b1a); b1b = dot2(wg[1][i], h1, b1b);
            b2a = dot2(wg[2][i], h0, b2a); b2b = dot2(wg[2][i], h1, b2b);
            b3a = dot2(wg[3][i], h0, b3a); b3b = dot2(wg[3][i], h1, b3b);
            b4a = dot2(wg[4][i], h0, b4a); b4b = dot2(wg[4][i], h1, b4b);
        }
        pB[kq][0][0][lane] = b0a; pB[kq][0][1][lane] = b1a; pB[kq][0][2][lane] = b2a;
        pB[kq][0][3][lane] = b3a; pB[kq][0][4][lane] = b4a;
        pB[kq][1][0][lane] = b0b; pB[kq][1][1][lane] = b1b; pB[kq][1][2][lane] = b2b;
        pB[kq][1][3][lane] = b3b; pB[kq][1][4][lane] = b4b;
        __syncthreads();
        // (6) cell update + outputs (tid<256: s,l)
        if (tid < 256) {
            float ai = pB[0][s][0][l] + pB[1][s][0][l] + pB[2][s][0][l] + pB[3][s][0][l] + xgg0;
            float af = pB[0][s][1][l] + pB[1][s][1][l] + pB[2][s][1][l] + pB[3][s][1][l] + xgg1;
            float ad = pB[0][s][2][l] + pB[1][s][2][l] + pB[2][s][2][l] + pB[3][s][2][l] + xgg2;
            float ag = pB[0][s][3][l] + pB[1][s][3][l] + pB[2][s][3][l] + pB[3][s][3][l] + xgg3;
            float ao = pB[0][s][4][l] + pB[1][s][4][l] + pB[2][s][4][l] + pB[3][s][4][l] + xgg4;
            float ig = fast_sig(ai);
            float fg = fast_sig(af);
            float dl = __expf(ad);
            float gt = tanhf(ag);
            float og = fast_sig(ao);
            float gc = fmaf(fg, cst, ig * gt);
            float df = cst - gc;
            float dtv = dt_time[row0 + s];
            cst = fmaf(df, __expf(-dl * dtv), gc);
            float hn = og * tanhf(cst);
            size_t go = (size_t)(row0 + s) * 512 + e * 128 + l;
            Gst[0 * GST_PLANE + go] = gc;
            Gst[1 * GST_PLANE + go] = df;
            Gst[2 * GST_PLANE + go] = dl;
            Gst[3 * GST_PLANE + go] = og;
            // pack h_new pairs -> hbuf parity (t+1)&1 via IC-direct atomic store
            float hi = __shfl_down(hn, 1, 64);
            if ((l & 1) == 0) {
                unsigned* dst = hbuf
                    + (size_t)(((t + 1) & 1) * 64 + grp) * 512
                    + (e * 2 + s) * 64 + (l >> 1);
                __hip_atomic_store(dst, pack2h(hn, hi), __ATOMIC_RELAXED,
                                   __HIP_MEMORY_SCOPE_AGENT);
            }
            // lambda reduce
            float lm = av * hn;
            #pragma unroll
            for (int off = 32; off > 0; off >>= 1) lm += __shfl_down(lm, off, 64);
            if ((tid & 63) == 0) red[tid >> 6] = lm;
        }
        __syncthreads();   // drains vmcnt(0): h stores are at IC before flag add
        if (tid == 0) {
            lam_out[(row0 + 0) * 4 + e] = red[0] + red[1];
            lam_out[(row0 + 1) * 4 + e] = red[2] + red[3];
            __hip_atomic_fetch_add(&gflag[t], 1, __ATOMIC_RELAXED,
                                   __HIP_MEMORY_SCOPE_AGENT);
        }
    }
}

// ---------------- K3: trapezoid integrals, 1 block per (t,b) ----------------
__global__ __launch_bounds__(256) void k3_trap(
    const float* __restrict__ Gst, const float* __restrict__ dt_time,
    const float* __restrict__ alpha, float* __restrict__ integ_out)
{
    __shared__ float red[4][2];
    const int row = blockIdx.x;
    const int tid = threadIdx.x;
    const float dtv = dt_time[row];
    const int base = row * 512;
    const int pA = tid, pB = tid + 256;
    float gcA = Gst[0 * GST_PLANE + base + pA];
    float gcB = Gst[0 * GST_PLANE + base + pB];
    float dfA = Gst[1 * GST_PLANE + base + pA];
    float dfB = Gst[1 * GST_PLANE + base + pB];
    float dlA = Gst[2 * GST_PLANE + base + pA];
    float dlB = Gst[2 * GST_PLANE + base + pB];
    float oA  = Gst[3 * GST_PLANE + base + pA];
    float oB  = Gst[3 * GST_PLANE + base + pB];
    float aoA = alpha[pA] * oA;
    float aoB = alpha[pB] * oB;
    float g2A = 2.f * gcA, d2A = 2.f * dfA;
    float g2B = 2.f * gcB, d2B = 2.f * dfB;
    float qA = dlA * dtv, qB = dlB * dtv;
    float rA = __expf(-qA * 0.01f);
    float rB = __expf(-qB * 0.01f);
    float E100A = __expf(-qA);
    float E100B = __expf(-qB);
    float sA = 0.5f * (__fdividef(1.f, __expf(g2A + d2A) + 1.f)
                     + __fdividef(1.f, __expf(fmaf(d2A, E100A, g2A)) + 1.f));
    float sB = 0.5f * (__fdividef(1.f, __expf(g2B + d2B) + 1.f)
                     + __fdividef(1.f, __expf(fmaf(d2B, E100B, g2B)) + 1.f));
    float EA = rA, EB = rB;
    for (int k = 1; k < 100; k++) {
        sA += __fdividef(1.f, __expf(fmaf(d2A, EA, g2A)) + 1.f);
        sB += __fdividef(1.f, __expf(fmaf(d2B, EB, g2B)) + 1.f);
        EA *= rA;
        EB *= rB;
    }
    float vA = aoA * (100.f - 2.f * sA);
    float vB = aoB * (100.f - 2.f * sB);
    #pragma unroll
    for (int off = 32; off > 0; off >>= 1) {
        vA += __shfl_down(vA, off, 64);
        vB += __shfl_down(vB, off, 64);
    }
    const int wv = tid >> 6;
    if ((tid & 63) == 0) { red[wv][0] = vA; red[wv][1] = vB; }
    __syncthreads();
    if (tid < 4) {
        float v = (tid < 2) ? (red[2 * tid][0] + red[2 * tid + 1][0])
                            : (red[2 * (tid - 2)][1] + red[2 * (tid - 2) + 1][1]);
        integ_out[row * 4 + tid] = v * (dtv * 0.01f);
    }
}

extern "C" void kernel_launch(void* const* d_in, const int* in_sizes, int n_in,
                              void* d_out, int out_size, void* d_ws, size_t ws_size,
                              hipStream_t stream)
{
    const float* x_time  = (const float*)d_in[0];
    const float* dt_time = (const float*)d_in[1];
    const float* Wh_w = (const float*)d_in[2];
    const float* Wh_b = (const float*)d_in[3];
    const float* Wi_w = (const float*)d_in[4];
    const float* Wi_b = (const float*)d_in[5];
    const float* Wf_w = (const float*)d_in[6];
    const float* Wf_b = (const float*)d_in[7];
    const float* Wd_w = (const float*)d_in[8];
    const float* Wd_b = (const float*)d_in[9];
    const float* Wg_w = (const float*)d_in[10];
    const float* Wg_b = (const float*)d_in[11];
    const float* Wo_w = (const float*)d_in[12];
    const float* Wo_b = (const float*)d_in[13];
    const float* alpha = (const float*)d_in[14];

    float* ws = (float*)d_ws;
    float* XG   = ws + OFF_XG;
    float* Gst  = ws + OFF_GST;
    unsigned* hbuf = (unsigned*)(ws + OFF_HBUF);
    int*   flags = (int*)(ws + OFF_FLAGS);
    float* lam_out   = (float*)d_out;
    float* integ_out = lam_out + 32 * 128 * 4;

    k0_pack<<<3072, 256, 0, stream>>>(Wh_w, Wh_b, Wi_w, Wi_b, Wf_w, Wf_b,
                                      Wd_w, Wd_b, Wg_w, Wg_b, Wo_w, Wo_b, ws);
    k1_xproj<<<3072, 256, 0, stream>>>(x_time, ws, XG);
    k2_recur<<<256, 512, 0, stream>>>(
        (const unsigned*)(ws + OFF_WHHH), (const unsigned*)(ws + OFF_WGH),
        XG, dt_time, alpha, Gst, hbuf, flags, lam_out);
    k3_trap<<<4096, 256, 0, stream>>>(Gst, dt_time, alpha, integ_out);
}